// Round 1
// baseline (1017.186 us; speedup 1.0000x reference)
//
#include <hip/hip_runtime.h>

#define N_NODES 100000
#define N_EDGES 1250000
#define C 64

// Wave-per-edge scatter: lane c handles channel c.
// Gather x[src] row (coalesced 256B per wave), atomicAdd into agg[dst] row
// (coalesced 64 consecutive fp32 atomics). Lane 0 bumps the degree count.
__global__ void scatter_mean_kernel(const float* __restrict__ feat,
                                    const int* __restrict__ src,
                                    const int* __restrict__ dst,
                                    float* __restrict__ agg,
                                    float* __restrict__ cnt,
                                    int n_edges, int do_cnt) {
    long long gtid = (long long)blockIdx.x * blockDim.x + threadIdx.x;
    int e = (int)(gtid >> 6);
    int lane = (int)(gtid & 63);
    if (e >= n_edges) return;
    int s = src[e];
    int d = dst[e];
    float v = feat[(long long)s * C + lane];
    atomicAdd(&agg[(long long)d * C + lane], v);
    if (do_cnt && lane == 0) atomicAdd(&cnt[d], 1.0f);
}

// One thread per (node, out_channel). Wave = one node's 64 output channels.
// agg/x row reads are wave-uniform (broadcast, L1-hit); weights staged in LDS,
// lanes read s_w[k*64+ch] stride-1 (2 lanes/bank = free on gfx950).
__global__ void sage_prelu_kernel(const float* __restrict__ agg,
                                  const float* __restrict__ cnt,
                                  const float* __restrict__ x,
                                  const float* __restrict__ w_l,
                                  const float* __restrict__ b_l,
                                  const float* __restrict__ w_r,
                                  const float* __restrict__ a,
                                  float* __restrict__ out) {
    __shared__ float s_wl[C * C];
    __shared__ float s_wr[C * C];
    __shared__ float s_b[C];
    __shared__ float s_a[C];
    for (int i = threadIdx.x; i < C * C; i += blockDim.x) {
        s_wl[i] = w_l[i];
        s_wr[i] = w_r[i];
    }
    if (threadIdx.x < C) {
        s_b[threadIdx.x] = b_l[threadIdx.x];
        s_a[threadIdx.x] = a[threadIdx.x];
    }
    __syncthreads();

    long long gtid = (long long)blockIdx.x * blockDim.x + threadIdx.x;
    if (gtid >= (long long)N_NODES * C) return;
    int node = (int)(gtid >> 6);
    int ch = (int)(gtid & 63);

    float inv = 1.0f / fmaxf(cnt[node], 1.0f);
    const float* arow = agg + (long long)node * C;
    const float* xrow = x + (long long)node * C;

    float acc = s_b[ch];
#pragma unroll
    for (int k = 0; k < C; ++k) {
        acc += arow[k] * inv * s_wl[k * C + ch] + xrow[k] * s_wr[k * C + ch];
    }
    out[gtid] = acc >= 0.0f ? acc : s_a[ch] * acc;
}

extern "C" void kernel_launch(void* const* d_in, const int* in_sizes, int n_in,
                              void* d_out, int out_size, void* d_ws, size_t ws_size,
                              hipStream_t stream) {
    const float* x    = (const float*)d_in[0];
    const int*   ei   = (const int*)d_in[1];
    const float* w_l0 = (const float*)d_in[2];
    const float* b_l0 = (const float*)d_in[3];
    const float* w_r0 = (const float*)d_in[4];
    const float* a0   = (const float*)d_in[5];
    const float* w_l1 = (const float*)d_in[6];
    const float* b_l1 = (const float*)d_in[7];
    const float* w_r1 = (const float*)d_in[8];
    const float* a1   = (const float*)d_in[9];
    float* out = (float*)d_out;

    // Workspace layout (floats): agg[N*C] | cnt[N] | h1[N*C]
    float* agg = (float*)d_ws;
    float* cnt = agg + (size_t)N_NODES * C;
    float* h1  = cnt + (size_t)N_NODES;

    const int* src = ei;             // edge_index[0, :]
    const int* dst = ei + N_EDGES;   // edge_index[1, :]

    hipMemsetAsync(agg, 0, (size_t)N_NODES * C * sizeof(float), stream);
    hipMemsetAsync(cnt, 0, (size_t)N_NODES * sizeof(float), stream);

    const long long scatter_threads = (long long)N_EDGES * 64;
    const int sblocks = (int)((scatter_threads + 255) / 256);
    const int nblocks = (int)(((long long)N_NODES * C + 255) / 256);

    // Layer 0
    scatter_mean_kernel<<<sblocks, 256, 0, stream>>>(x, src, dst, agg, cnt, N_EDGES, 1);
    sage_prelu_kernel<<<nblocks, 256, 0, stream>>>(agg, cnt, x, w_l0, b_l0, w_r0, a0, h1);

    // Layer 1 (reuse cnt; re-zero agg)
    hipMemsetAsync(agg, 0, (size_t)N_NODES * C * sizeof(float), stream);
    scatter_mean_kernel<<<sblocks, 256, 0, stream>>>(h1, src, dst, agg, cnt, N_EDGES, 0);
    sage_prelu_kernel<<<nblocks, 256, 0, stream>>>(agg, cnt, h1, w_l1, b_l1, w_r1, a1, out);
}

// Round 2
// 871.499 us; speedup vs baseline: 1.1672x; 1.1672x over previous
//
#include <hip/hip_runtime.h>

#define N_NODES 100000
#define N_EDGES 1250000
#define C 64

// K1: degree histogram (int atomics over 400 KB -- cheap vs fp32 row atomics)
__global__ void hist_kernel(const int* __restrict__ dst, int* __restrict__ cnt) {
    int e = blockIdx.x * blockDim.x + threadIdx.x;
    if (e < N_EDGES) atomicAdd(&cnt[dst[e]], 1);
}

// K2: single-block exclusive scan of cnt[N] -> offsets[N+1]; also initializes cursor.
// 1024 threads x 98-element serial chunks + Hillis-Steele block scan.
__global__ __launch_bounds__(1024) void scan_kernel(const int* __restrict__ cnt,
                                                    int* __restrict__ offsets,
                                                    int* __restrict__ cursor) {
    __shared__ int s[1024];
    const int tid = threadIdx.x;
    const int chunk = (N_NODES + 1023) / 1024;  // 98
    int beg = tid * chunk;
    int end = min(beg + chunk, N_NODES);
    int sum = 0;
    for (int i = beg; i < end; ++i) sum += cnt[i];
    s[tid] = sum;
    __syncthreads();
    for (int off = 1; off < 1024; off <<= 1) {
        int v = (tid >= off) ? s[tid - off] : 0;
        __syncthreads();
        s[tid] += v;
        __syncthreads();
    }
    int run = (tid == 0) ? 0 : s[tid - 1];
    for (int i = beg; i < end; ++i) {
        offsets[i] = run;
        cursor[i] = run;
        run += cnt[i];
    }
    if (tid == 0) offsets[N_NODES] = s[1023];
}

// K3: counting-sort edge sources into dst-buckets
__global__ void bucket_kernel(const int* __restrict__ src, const int* __restrict__ dst,
                              int* __restrict__ cursor, int* __restrict__ sorted_src) {
    int e = blockIdx.x * blockDim.x + threadIdx.x;
    if (e < N_EDGES) {
        int pos = atomicAdd(&cursor[dst[e]], 1);
        sorted_src[pos] = src[e];
    }
}

// K4: fused gather-mean + SAGE (dual 64x64 GEMV) + PReLU. One wave per node,
// lane = channel. Neighbor rows gathered coalesced (64x4B = 256B per row);
// 4-wide batched loads for memory-level parallelism. Weights staged in LDS
// (s_w[k*64+lane]: stride-1 across lanes = 2-way bank alias = free).
__global__ __launch_bounds__(256) void sage_fused_kernel(
        const float* __restrict__ feat,
        const int* __restrict__ offsets,
        const int* __restrict__ sorted_src,
        const float* __restrict__ w_l, const float* __restrict__ b_l,
        const float* __restrict__ w_r, const float* __restrict__ a,
        float* __restrict__ out) {
    __shared__ float s_wl[C * C];
    __shared__ float s_wr[C * C];
    __shared__ float s_b[C];
    __shared__ float s_a[C];
    for (int i = threadIdx.x; i < C * C; i += 256) {
        s_wl[i] = w_l[i];
        s_wr[i] = w_r[i];
    }
    if (threadIdx.x < C) {
        s_b[threadIdx.x] = b_l[threadIdx.x];
        s_a[threadIdx.x] = a[threadIdx.x];
    }
    __syncthreads();

    const int lane = threadIdx.x & 63;
    const int node = blockIdx.x * 4 + (threadIdx.x >> 6);  // grid sized exactly
    if (node >= N_NODES) return;

    const int beg = offsets[node];
    const int end = offsets[node + 1];
    const int deg = end - beg;

    float acc = 0.0f;
    for (int base = beg; base < end; base += 64) {
        int rem = end - base;
        int lim = rem < 64 ? rem : 64;
        int nidx = (lane < lim) ? sorted_src[base + lane] : 0;
        int j = 0;
        for (; j + 4 <= lim; j += 4) {
            int s0 = __shfl(nidx, j);
            int s1 = __shfl(nidx, j + 1);
            int s2 = __shfl(nidx, j + 2);
            int s3 = __shfl(nidx, j + 3);
            float v0 = feat[(long long)s0 * C + lane];
            float v1 = feat[(long long)s1 * C + lane];
            float v2 = feat[(long long)s2 * C + lane];
            float v3 = feat[(long long)s3 * C + lane];
            acc += (v0 + v1) + (v2 + v3);
        }
        for (; j < lim; ++j) {
            int sj = __shfl(nidx, j);
            acc += feat[(long long)sj * C + lane];
        }
    }
    const float mval = acc / (float)max(deg, 1);
    const float xval = feat[(long long)node * C + lane];

    float o = s_b[lane];
#pragma unroll
    for (int k = 0; k < C; ++k) {
        float mk = __shfl(mval, k);
        float xk = __shfl(xval, k);
        o += mk * s_wl[k * C + lane] + xk * s_wr[k * C + lane];
    }
    out[(long long)node * C + lane] = o >= 0.0f ? o : s_a[lane] * o;
}

extern "C" void kernel_launch(void* const* d_in, const int* in_sizes, int n_in,
                              void* d_out, int out_size, void* d_ws, size_t ws_size,
                              hipStream_t stream) {
    const float* x    = (const float*)d_in[0];
    const int*   ei   = (const int*)d_in[1];
    const float* w_l0 = (const float*)d_in[2];
    const float* b_l0 = (const float*)d_in[3];
    const float* w_r0 = (const float*)d_in[4];
    const float* a0   = (const float*)d_in[5];
    const float* w_l1 = (const float*)d_in[6];
    const float* b_l1 = (const float*)d_in[7];
    const float* w_r1 = (const float*)d_in[8];
    const float* a1   = (const float*)d_in[9];
    float* out = (float*)d_out;

    const int* src = ei;            // edge_index[0, :]
    const int* dst = ei + N_EDGES;  // edge_index[1, :]

    // Workspace layout: cnt[N] | offsets[N+1] | cursor[N] | sorted_src[E] | h1[N*C]
    int* cnt        = (int*)d_ws;
    int* offsets    = cnt + N_NODES;
    int* cursor     = offsets + (N_NODES + 1);
    int* sorted_src = cursor + N_NODES;
    float* h1       = (float*)(sorted_src + N_EDGES);

    hipMemsetAsync(cnt, 0, (size_t)N_NODES * sizeof(int), stream);

    const int eblocks = (N_EDGES + 255) / 256;
    const int nblocks = N_NODES / 4;  // 25000, exact

    hist_kernel<<<eblocks, 256, 0, stream>>>(dst, cnt);
    scan_kernel<<<1, 1024, 0, stream>>>(cnt, offsets, cursor);
    bucket_kernel<<<eblocks, 256, 0, stream>>>(src, dst, cursor, sorted_src);

    sage_fused_kernel<<<nblocks, 256, 0, stream>>>(x, offsets, sorted_src,
                                                   w_l0, b_l0, w_r0, a0, h1);
    sage_fused_kernel<<<nblocks, 256, 0, stream>>>(h1, offsets, sorted_src,
                                                   w_l1, b_l1, w_r1, a1, out);
}

// Round 3
// 520.819 us; speedup vs baseline: 1.9531x; 1.6733x over previous
//
#include <hip/hip_runtime.h>

#define N_NODES 100000
#define N_EDGES 1250000
#define C 64
#define SCAN_NB 391  // ceil(100000/256)

// ---------------- CSR build ----------------

__global__ void hist_kernel(const int* __restrict__ dst, int* __restrict__ cnt) {
    int e = blockIdx.x * blockDim.x + threadIdx.x;
    if (e < N_EDGES) atomicAdd(&cnt[dst[e]], 1);
}

// per-block sums of cnt
__global__ void scan1_kernel(const int* __restrict__ cnt, int* __restrict__ partial) {
    __shared__ int s[256];
    int i = blockIdx.x * 256 + threadIdx.x;
    int v = (i < N_NODES) ? cnt[i] : 0;
    s[threadIdx.x] = v;
    __syncthreads();
    for (int off = 128; off > 0; off >>= 1) {
        if (threadIdx.x < off) s[threadIdx.x] += s[threadIdx.x + off];
        __syncthreads();
    }
    if (threadIdx.x == 0) partial[blockIdx.x] = s[0];
}

// single-block inclusive scan of the 391 partials
__global__ __launch_bounds__(512) void scan2_kernel(int* __restrict__ partial) {
    __shared__ int s[512];
    int t = threadIdx.x;
    s[t] = (t < SCAN_NB) ? partial[t] : 0;
    __syncthreads();
    for (int off = 1; off < 512; off <<= 1) {
        int v = (t >= off) ? s[t - off] : 0;
        __syncthreads();
        s[t] += v;
        __syncthreads();
    }
    if (t < SCAN_NB) partial[t] = s[t];
}

// block-local exclusive scan + block prefix -> offsets & cursor
__global__ void scan3_kernel(const int* __restrict__ cnt, const int* __restrict__ partial,
                             int* __restrict__ offsets, int* __restrict__ cursor) {
    __shared__ int s[256];
    int i = blockIdx.x * 256 + threadIdx.x;
    int t = threadIdx.x;
    int v = (i < N_NODES) ? cnt[i] : 0;
    s[t] = v;
    __syncthreads();
    for (int off = 1; off < 256; off <<= 1) {
        int u = (t >= off) ? s[t - off] : 0;
        __syncthreads();
        s[t] += u;
        __syncthreads();
    }
    int excl = s[t] - v + (blockIdx.x ? partial[blockIdx.x - 1] : 0);
    if (i < N_NODES) {
        offsets[i] = excl;
        cursor[i] = excl;
    }
    if (i == 0) offsets[N_NODES] = N_EDGES;
}

__global__ void bucket_kernel(const int* __restrict__ src, const int* __restrict__ dst,
                              int* __restrict__ cursor, int* __restrict__ sorted_src) {
    int e = blockIdx.x * blockDim.x + threadIdx.x;
    if (e < N_EDGES) {
        int pos = atomicAdd(&cursor[dst[e]], 1);
        sorted_src[pos] = src[e];
    }
}

// ---------------- per-layer compute ----------------

// z = x @ W_l ; r = x @ W_r + b. Wave per node, lane = out channel.
// x row read once into registers, broadcast via v_readlane (unrolled constant k).
// Weights interleaved in LDS so the two reads per k fuse into ds_read2_b32.
// NOTE: no __restrict__ on x/r -- layer 1 calls with r aliasing x (row-aligned safe).
__global__ __launch_bounds__(256) void dense_kernel(
        const float* x,
        const float* __restrict__ w_l, const float* __restrict__ w_r,
        const float* __restrict__ b_l,
        float* __restrict__ z, float* r) {
    __shared__ float s_w[C * 2 * C];  // s_w[k*128 + c] = W_l[k][c]; +64 = W_r[k][c]
    for (int i = threadIdx.x; i < C * C; i += 256) {
        int k = i >> 6, c = i & 63;
        s_w[k * 128 + c] = w_l[i];
        s_w[k * 128 + 64 + c] = w_r[i];
    }
    __syncthreads();

    const int lane = threadIdx.x & 63;
    const int node = (blockIdx.x << 2) + (threadIdx.x >> 6);

    float xv = x[(size_t)node * C + lane];
    float az = 0.0f;
    float ar = b_l[lane];
#pragma unroll
    for (int k = 0; k < C; ++k) {
        float xk = __int_as_float(__builtin_amdgcn_readlane(__float_as_int(xv), k));
        az += xk * s_w[k * 128 + lane];
        ar += xk * s_w[k * 128 + 64 + lane];
    }
    z[(size_t)node * C + lane] = az;
    r[(size_t)node * C + lane] = ar;
}

// h = PReLU( mean_j z[nbr_j] + r ). Wave per node, lane = channel. No LDS ->
// full occupancy; 8 row-loads in flight per wave; neighbor indices are
// wave-uniform (scalar path). out may alias r (row-aligned, read-before-write).
__global__ __launch_bounds__(256) void gather_kernel(
        const float* __restrict__ z,
        const float* r,
        const int* __restrict__ offsets,
        const int* __restrict__ sorted_src,
        const float* __restrict__ a,
        float* out) {
    const int lane = threadIdx.x & 63;
    const int node = (blockIdx.x << 2) + (threadIdx.x >> 6);

    const int beg = offsets[node];
    const int deg = offsets[node + 1] - beg;

    float acc = 0.0f;
    for (int j = 0; j < deg; j += 8) {
        int last = deg - 1;
        int i0 = beg + min(j + 0, last);
        int i1 = beg + min(j + 1, last);
        int i2 = beg + min(j + 2, last);
        int i3 = beg + min(j + 3, last);
        int i4 = beg + min(j + 4, last);
        int i5 = beg + min(j + 5, last);
        int i6 = beg + min(j + 6, last);
        int i7 = beg + min(j + 7, last);
        int s0 = sorted_src[i0];
        int s1 = sorted_src[i1];
        int s2 = sorted_src[i2];
        int s3 = sorted_src[i3];
        int s4 = sorted_src[i4];
        int s5 = sorted_src[i5];
        int s6 = sorted_src[i6];
        int s7 = sorted_src[i7];
        float v0 = z[(size_t)s0 * C + lane];
        float v1 = z[(size_t)s1 * C + lane];
        float v2 = z[(size_t)s2 * C + lane];
        float v3 = z[(size_t)s3 * C + lane];
        float v4 = z[(size_t)s4 * C + lane];
        float v5 = z[(size_t)s5 * C + lane];
        float v6 = z[(size_t)s6 * C + lane];
        float v7 = z[(size_t)s7 * C + lane];
        float sum = v0;
        sum += (j + 1 < deg) ? v1 : 0.0f;
        sum += (j + 2 < deg) ? v2 : 0.0f;
        sum += (j + 3 < deg) ? v3 : 0.0f;
        sum += (j + 4 < deg) ? v4 : 0.0f;
        sum += (j + 5 < deg) ? v5 : 0.0f;
        sum += (j + 6 < deg) ? v6 : 0.0f;
        sum += (j + 7 < deg) ? v7 : 0.0f;
        acc += sum;
    }
    float rv = r[(size_t)node * C + lane];
    float h = acc / (float)max(deg, 1) + rv;
    float av = a[lane];
    out[(size_t)node * C + lane] = h >= 0.0f ? h : av * h;
}

extern "C" void kernel_launch(void* const* d_in, const int* in_sizes, int n_in,
                              void* d_out, int out_size, void* d_ws, size_t ws_size,
                              hipStream_t stream) {
    const float* x    = (const float*)d_in[0];
    const int*   ei   = (const int*)d_in[1];
    const float* w_l0 = (const float*)d_in[2];
    const float* b_l0 = (const float*)d_in[3];
    const float* w_r0 = (const float*)d_in[4];
    const float* a0   = (const float*)d_in[5];
    const float* w_l1 = (const float*)d_in[6];
    const float* b_l1 = (const float*)d_in[7];
    const float* w_r1 = (const float*)d_in[8];
    const float* a1   = (const float*)d_in[9];
    float* out = (float*)d_out;

    const int* src = ei;            // edge_index[0, :]
    const int* dst = ei + N_EDGES;  // edge_index[1, :]

    // ws: cnt[N] | partial[512] | offsets[N+1] | cursor[N] | sorted_src[E] | A[N*C] | B[N*C]
    int* cnt        = (int*)d_ws;
    int* partial    = cnt + N_NODES;
    int* offsets    = partial + 512;
    int* cursor     = offsets + (N_NODES + 1);
    int* sorted_src = cursor + N_NODES;
    float* A        = (float*)(sorted_src + N_EDGES);  // z buffer
    float* B        = A + (size_t)N_NODES * C;         // r / h buffer

    hipMemsetAsync(cnt, 0, (size_t)N_NODES * sizeof(int), stream);

    const int eblocks = (N_EDGES + 255) / 256;
    const int nblocks = N_NODES / 4;  // exact

    hist_kernel<<<eblocks, 256, 0, stream>>>(dst, cnt);
    scan1_kernel<<<SCAN_NB, 256, 0, stream>>>(cnt, partial);
    scan2_kernel<<<1, 512, 0, stream>>>(partial);
    scan3_kernel<<<SCAN_NB, 256, 0, stream>>>(cnt, partial, offsets, cursor);
    bucket_kernel<<<eblocks, 256, 0, stream>>>(src, dst, cursor, sorted_src);

    // Layer 0: z=A, r=B; gather writes h1 into B (row-aligned alias with r)
    dense_kernel<<<nblocks, 256, 0, stream>>>(x, w_l0, w_r0, b_l0, A, B);
    gather_kernel<<<nblocks, 256, 0, stream>>>(A, B, offsets, sorted_src, a0, B);

    // Layer 1: x=B, z=A, r=B (in-place, row-aligned safe); gather -> d_out
    dense_kernel<<<nblocks, 256, 0, stream>>>(B, w_l1, w_r1, b_l1, A, B);
    gather_kernel<<<nblocks, 256, 0, stream>>>(A, B, offsets, sorted_src, a1, out);
}

// Round 4
// 392.347 us; speedup vs baseline: 2.5926x; 1.3274x over previous
//
#include <hip/hip_runtime.h>

#define N_NODES 100000
#define N_EDGES 1250000
#define C 64
#define SCAN_NB 391      // ceil(100000/256)
#define SHARD_SZ 12500   // N_NODES / 8 exactly
#define COHORT 128       // blocks per shard in bucket_kernel

// ---------------- CSR build ----------------

__global__ void hist_kernel(const int* __restrict__ dst, int* __restrict__ cnt) {
    int e = blockIdx.x * blockDim.x + threadIdx.x;
    if (e < N_EDGES) atomicAdd(&cnt[dst[e]], 1);
}

__global__ void scan1_kernel(const int* __restrict__ cnt, int* __restrict__ partial) {
    __shared__ int s[256];
    int i = blockIdx.x * 256 + threadIdx.x;
    int v = (i < N_NODES) ? cnt[i] : 0;
    s[threadIdx.x] = v;
    __syncthreads();
    for (int off = 128; off > 0; off >>= 1) {
        if (threadIdx.x < off) s[threadIdx.x] += s[threadIdx.x + off];
        __syncthreads();
    }
    if (threadIdx.x == 0) partial[blockIdx.x] = s[0];
}

__global__ __launch_bounds__(512) void scan2_kernel(int* __restrict__ partial) {
    __shared__ int s[512];
    int t = threadIdx.x;
    s[t] = (t < SCAN_NB) ? partial[t] : 0;
    __syncthreads();
    for (int off = 1; off < 512; off <<= 1) {
        int v = (t >= off) ? s[t - off] : 0;
        __syncthreads();
        s[t] += v;
        __syncthreads();
    }
    if (t < SCAN_NB) partial[t] = s[t];
}

__global__ void scan3_kernel(const int* __restrict__ cnt, const int* __restrict__ partial,
                             int* __restrict__ offsets, int* __restrict__ cursor) {
    __shared__ int s[256];
    int i = blockIdx.x * 256 + threadIdx.x;
    int t = threadIdx.x;
    int v = (i < N_NODES) ? cnt[i] : 0;
    s[t] = v;
    __syncthreads();
    for (int off = 1; off < 256; off <<= 1) {
        int u = (t >= off) ? s[t - off] : 0;
        __syncthreads();
        s[t] += u;
        __syncthreads();
    }
    int excl = s[t] - v + (blockIdx.x ? partial[blockIdx.x - 1] : 0);
    if (i < N_NODES) {
        offsets[i] = excl;
        cursor[i] = excl;
    }
    if (i == 0) offsets[N_NODES] = N_EDGES;
}

// XCD-sharded counting-sort scatter: shard = blockIdx&7 handles dst range
// [shard*12500, +12500). Each shard's writes hit a contiguous ~640KB slice of
// sorted_src, staying dirty-resident in one L2 until lines fill -> kills the
// 17x partial-line write amplification. Exact disjoint partition of edges, so
// correctness does not depend on the block->XCD mapping.
__global__ __launch_bounds__(256) void bucket_kernel(const int* __restrict__ src,
                                                     const int* __restrict__ dst,
                                                     int* __restrict__ cursor,
                                                     int* __restrict__ sorted_src) {
    const int shard = blockIdx.x & 7;
    const int cohort = blockIdx.x >> 3;
    const int lo = shard * SHARD_SZ;
    const int hi = lo + SHARD_SZ;
    for (int e = cohort * 256 + threadIdx.x; e < N_EDGES; e += COHORT * 256) {
        int d = dst[e];
        if (d >= lo && d < hi) {
            int pos = atomicAdd(&cursor[d], 1);
            sorted_src[pos] = src[e];
        }
    }
}

// ---------------- per-layer compute ----------------

// z = x @ W_l ; r = x @ W_r + b. Register-tiled fp32 GEMM:
// block = 256 threads = 4 waves, 64-node tile. Lane computes 4 nodes x 4
// channels for both z and r (32 accumulators). Per k: 2x ds_read_b128
// (weights), 4x ds_read_b32 (x, +65 pad -> conflict-free), 32 FMAs.
// In-place safe (layer 1: r aliases x): block stages its x tile to LDS,
// __syncthreads, then writes only its own tile rows.
__global__ __launch_bounds__(256) void dense_kernel(
        const float* x,
        const float* __restrict__ wl, const float* __restrict__ wr,
        const float* __restrict__ bl,
        float* __restrict__ z, float* r, int n_nodes) {
    __shared__ float s_w[C][2 * C];   // [k][c]: c<64 -> W_l, c>=64 -> W_r (32 KB)
    __shared__ float s_x[64][C + 1];  // x tile, +1 pad (16.25 KB)

    const int t = threadIdx.x;
    const int base = blockIdx.x * 64;

    for (int i = t; i < C * C; i += 256) {
        int k = i >> 6, c = i & 63;
        s_w[k][c] = wl[i];
        s_w[k][64 + c] = wr[i];
    }
    // stage x: 1024 float4s, coalesced
    for (int i = t; i < 1024; i += 256) {
        int n = i >> 4;
        int kq = i & 15;
        float4 v = make_float4(0.f, 0.f, 0.f, 0.f);
        if (base + n < n_nodes) v = ((const float4*)x)[((size_t)(base + n) << 4) + kq];
        s_x[n][kq * 4 + 0] = v.x;
        s_x[n][kq * 4 + 1] = v.y;
        s_x[n][kq * 4 + 2] = v.z;
        s_x[n][kq * 4 + 3] = v.w;
    }
    __syncthreads();

    const int lane = t & 63;
    const int wv = t >> 6;
    const int cg = lane & 15;       // channel quad
    const int q = lane >> 4;        // node quad
    const int n0 = wv * 16 + 4 * q; // first of this lane's 4 tile-local nodes

    float4 bv = ((const float4*)bl)[cg];
    float accz[4][4];
    float accr[4][4];
#pragma unroll
    for (int i = 0; i < 4; ++i) {
        accz[i][0] = accz[i][1] = accz[i][2] = accz[i][3] = 0.f;
        accr[i][0] = bv.x; accr[i][1] = bv.y; accr[i][2] = bv.z; accr[i][3] = bv.w;
    }

#pragma unroll 8
    for (int k = 0; k < C; ++k) {
        float4 wlv = *(const float4*)&s_w[k][4 * cg];
        float4 wrv = *(const float4*)&s_w[k][64 + 4 * cg];
        float xk[4];
#pragma unroll
        for (int i = 0; i < 4; ++i) xk[i] = s_x[n0 + i][k];
#pragma unroll
        for (int i = 0; i < 4; ++i) {
            accz[i][0] += xk[i] * wlv.x;
            accz[i][1] += xk[i] * wlv.y;
            accz[i][2] += xk[i] * wlv.z;
            accz[i][3] += xk[i] * wlv.w;
            accr[i][0] += xk[i] * wrv.x;
            accr[i][1] += xk[i] * wrv.y;
            accr[i][2] += xk[i] * wrv.z;
            accr[i][3] += xk[i] * wrv.w;
        }
    }

#pragma unroll
    for (int i = 0; i < 4; ++i) {
        size_t gn = (size_t)base + n0 + i;
        if (gn < (size_t)n_nodes) {
            ((float4*)z)[gn * 16 + cg] = make_float4(accz[i][0], accz[i][1], accz[i][2], accz[i][3]);
            ((float4*)r)[gn * 16 + cg] = make_float4(accr[i][0], accr[i][1], accr[i][2], accr[i][3]);
        }
    }
}

// h = PReLU( mean_j z[nbr_j] + r ). Wave per node, lane = channel, no LDS.
__global__ __launch_bounds__(256) void gather_kernel(
        const float* __restrict__ z,
        const float* r,
        const int* __restrict__ offsets,
        const int* __restrict__ sorted_src,
        const float* __restrict__ a,
        float* out) {
    const int lane = threadIdx.x & 63;
    const int node = (blockIdx.x << 2) + (threadIdx.x >> 6);

    const int beg = offsets[node];
    const int deg = offsets[node + 1] - beg;

    float acc = 0.0f;
    for (int j = 0; j < deg; j += 8) {
        int last = deg - 1;
        int s0 = sorted_src[beg + min(j + 0, last)];
        int s1 = sorted_src[beg + min(j + 1, last)];
        int s2 = sorted_src[beg + min(j + 2, last)];
        int s3 = sorted_src[beg + min(j + 3, last)];
        int s4 = sorted_src[beg + min(j + 4, last)];
        int s5 = sorted_src[beg + min(j + 5, last)];
        int s6 = sorted_src[beg + min(j + 6, last)];
        int s7 = sorted_src[beg + min(j + 7, last)];
        float v0 = z[(size_t)s0 * C + lane];
        float v1 = z[(size_t)s1 * C + lane];
        float v2 = z[(size_t)s2 * C + lane];
        float v3 = z[(size_t)s3 * C + lane];
        float v4 = z[(size_t)s4 * C + lane];
        float v5 = z[(size_t)s5 * C + lane];
        float v6 = z[(size_t)s6 * C + lane];
        float v7 = z[(size_t)s7 * C + lane];
        float sum = v0;
        sum += (j + 1 < deg) ? v1 : 0.0f;
        sum += (j + 2 < deg) ? v2 : 0.0f;
        sum += (j + 3 < deg) ? v3 : 0.0f;
        sum += (j + 4 < deg) ? v4 : 0.0f;
        sum += (j + 5 < deg) ? v5 : 0.0f;
        sum += (j + 6 < deg) ? v6 : 0.0f;
        sum += (j + 7 < deg) ? v7 : 0.0f;
        acc += sum;
    }
    float rv = r[(size_t)node * C + lane];
    float h = acc / (float)max(deg, 1) + rv;
    float av = a[lane];
    out[(size_t)node * C + lane] = h >= 0.0f ? h : av * h;
}

extern "C" void kernel_launch(void* const* d_in, const int* in_sizes, int n_in,
                              void* d_out, int out_size, void* d_ws, size_t ws_size,
                              hipStream_t stream) {
    const float* x    = (const float*)d_in[0];
    const int*   ei   = (const int*)d_in[1];
    const float* w_l0 = (const float*)d_in[2];
    const float* b_l0 = (const float*)d_in[3];
    const float* w_r0 = (const float*)d_in[4];
    const float* a0   = (const float*)d_in[5];
    const float* w_l1 = (const float*)d_in[6];
    const float* b_l1 = (const float*)d_in[7];
    const float* w_r1 = (const float*)d_in[8];
    const float* a1   = (const float*)d_in[9];
    float* out = (float*)d_out;

    const int* src = ei;            // edge_index[0, :]
    const int* dst = ei + N_EDGES;  // edge_index[1, :]

    // ws: cnt[N] | partial[512] | offsets[N+1] | cursor[N] | sorted_src[E] | A[N*C] | B[N*C]
    int* cnt        = (int*)d_ws;
    int* partial    = cnt + N_NODES;
    int* offsets    = partial + 512;
    int* cursor     = offsets + (N_NODES + 1);
    int* sorted_src = cursor + N_NODES;
    float* A        = (float*)(sorted_src + N_EDGES);  // z buffer
    float* B        = A + (size_t)N_NODES * C;         // r / h buffer

    hipMemsetAsync(cnt, 0, (size_t)N_NODES * sizeof(int), stream);

    const int eblocks = (N_EDGES + 255) / 256;
    const int nblocks = N_NODES / 4;          // gather grid (exact)
    const int dblocks = (N_NODES + 63) / 64;  // dense grid = 1563

    hist_kernel<<<eblocks, 256, 0, stream>>>(dst, cnt);
    scan1_kernel<<<SCAN_NB, 256, 0, stream>>>(cnt, partial);
    scan2_kernel<<<1, 512, 0, stream>>>(partial);
    scan3_kernel<<<SCAN_NB, 256, 0, stream>>>(cnt, partial, offsets, cursor);
    bucket_kernel<<<8 * COHORT, 256, 0, stream>>>(src, dst, cursor, sorted_src);

    // Layer 0: z=A, r=B; gather writes h1 into B (row-aligned alias with r)
    dense_kernel<<<dblocks, 256, 0, stream>>>(x, w_l0, w_r0, b_l0, A, B, N_NODES);
    gather_kernel<<<nblocks, 256, 0, stream>>>(A, B, offsets, sorted_src, a0, B);

    // Layer 1: x=B, z=A, r=B (in-place per-block safe); gather -> d_out
    dense_kernel<<<dblocks, 256, 0, stream>>>(B, w_l1, w_r1, b_l1, A, B, N_NODES);
    gather_kernel<<<nblocks, 256, 0, stream>>>(A, B, offsets, sorted_src, a1, out);
}

// Round 5
// 356.246 us; speedup vs baseline: 2.8553x; 1.1013x over previous
//
#include <hip/hip_runtime.h>
#include <hip/hip_fp16.h>

#define N_NODES 100000
#define N_EDGES 1250000
#define C 64
#define SCAN_NB 391      // ceil(100000/256)
#define SHARD_SZ 12500   // N_NODES / 8 exactly
#define COHORT 128       // blocks per shard in bucket_kernel

// ---------------- CSR build ----------------

__global__ void hist_kernel(const int* __restrict__ dst, int* __restrict__ cnt) {
    int e = blockIdx.x * blockDim.x + threadIdx.x;
    if (e < N_EDGES) atomicAdd(&cnt[dst[e]], 1);
}

__global__ void scan1_kernel(const int* __restrict__ cnt, int* __restrict__ partial) {
    __shared__ int s[256];
    int i = blockIdx.x * 256 + threadIdx.x;
    int v = (i < N_NODES) ? cnt[i] : 0;
    s[threadIdx.x] = v;
    __syncthreads();
    for (int off = 128; off > 0; off >>= 1) {
        if (threadIdx.x < off) s[threadIdx.x] += s[threadIdx.x + off];
        __syncthreads();
    }
    if (threadIdx.x == 0) partial[blockIdx.x] = s[0];
}

__global__ __launch_bounds__(512) void scan2_kernel(int* __restrict__ partial) {
    __shared__ int s[512];
    int t = threadIdx.x;
    s[t] = (t < SCAN_NB) ? partial[t] : 0;
    __syncthreads();
    for (int off = 1; off < 512; off <<= 1) {
        int v = (t >= off) ? s[t - off] : 0;
        __syncthreads();
        s[t] += v;
        __syncthreads();
    }
    if (t < SCAN_NB) partial[t] = s[t];
}

__global__ void scan3_kernel(const int* __restrict__ cnt, const int* __restrict__ partial,
                             int* __restrict__ offsets, int* __restrict__ cursor) {
    __shared__ int s[256];
    int i = blockIdx.x * 256 + threadIdx.x;
    int t = threadIdx.x;
    int v = (i < N_NODES) ? cnt[i] : 0;
    s[t] = v;
    __syncthreads();
    for (int off = 1; off < 256; off <<= 1) {
        int u = (t >= off) ? s[t - off] : 0;
        __syncthreads();
        s[t] += u;
        __syncthreads();
    }
    int excl = s[t] - v + (blockIdx.x ? partial[blockIdx.x - 1] : 0);
    if (i < N_NODES) {
        offsets[i] = excl;
        cursor[i] = excl;
    }
    if (i == 0) offsets[N_NODES] = N_EDGES;
}

// XCD-sharded counting-sort scatter (kills partial-line write amplification).
__global__ __launch_bounds__(256) void bucket_kernel(const int* __restrict__ src,
                                                     const int* __restrict__ dst,
                                                     int* __restrict__ cursor,
                                                     int* __restrict__ sorted_src) {
    const int shard = blockIdx.x & 7;
    const int cohort = blockIdx.x >> 3;
    const int lo = shard * SHARD_SZ;
    const int hi = lo + SHARD_SZ;
    for (int e = cohort * 256 + threadIdx.x; e < N_EDGES; e += COHORT * 256) {
        int d = dst[e];
        if (d >= lo && d < hi) {
            int pos = atomicAdd(&cursor[d], 1);
            sorted_src[pos] = src[e];
        }
    }
}

// ---------------- per-layer compute ----------------

// z = x @ W_l (fp16 out) ; r = x @ W_r + b (fp32). Register-tiled fp32 GEMM:
// lane computes 4 nodes x 4 channels x {z,r}. In-place safe for r aliasing x
// (tile staged to LDS before any write).
__global__ __launch_bounds__(256) void dense_kernel(
        const float* x,
        const float* __restrict__ wl, const float* __restrict__ wr,
        const float* __restrict__ bl,
        __half* __restrict__ z, float* r, int n_nodes) {
    __shared__ float s_w[C][2 * C];   // [k][c]: c<64 -> W_l, c>=64 -> W_r
    __shared__ float s_x[64][C + 1];  // x tile, +1 pad

    const int t = threadIdx.x;
    const int base = blockIdx.x * 64;

    for (int i = t; i < C * C; i += 256) {
        int k = i >> 6, c = i & 63;
        s_w[k][c] = wl[i];
        s_w[k][64 + c] = wr[i];
    }
    for (int i = t; i < 1024; i += 256) {
        int n = i >> 4;
        int kq = i & 15;
        float4 v = make_float4(0.f, 0.f, 0.f, 0.f);
        if (base + n < n_nodes) v = ((const float4*)x)[((size_t)(base + n) << 4) + kq];
        s_x[n][kq * 4 + 0] = v.x;
        s_x[n][kq * 4 + 1] = v.y;
        s_x[n][kq * 4 + 2] = v.z;
        s_x[n][kq * 4 + 3] = v.w;
    }
    __syncthreads();

    const int lane = t & 63;
    const int wv = t >> 6;
    const int cg = lane & 15;
    const int q = lane >> 4;
    const int n0 = wv * 16 + 4 * q;

    float4 bv = ((const float4*)bl)[cg];
    float accz[4][4];
    float accr[4][4];
#pragma unroll
    for (int i = 0; i < 4; ++i) {
        accz[i][0] = accz[i][1] = accz[i][2] = accz[i][3] = 0.f;
        accr[i][0] = bv.x; accr[i][1] = bv.y; accr[i][2] = bv.z; accr[i][3] = bv.w;
    }

#pragma unroll 8
    for (int k = 0; k < C; ++k) {
        float4 wlv = *(const float4*)&s_w[k][4 * cg];
        float4 wrv = *(const float4*)&s_w[k][64 + 4 * cg];
        float xk[4];
#pragma unroll
        for (int i = 0; i < 4; ++i) xk[i] = s_x[n0 + i][k];
#pragma unroll
        for (int i = 0; i < 4; ++i) {
            accz[i][0] += xk[i] * wlv.x;
            accz[i][1] += xk[i] * wlv.y;
            accz[i][2] += xk[i] * wlv.z;
            accz[i][3] += xk[i] * wlv.w;
            accr[i][0] += xk[i] * wrv.x;
            accr[i][1] += xk[i] * wrv.y;
            accr[i][2] += xk[i] * wrv.z;
            accr[i][3] += xk[i] * wrv.w;
        }
    }

#pragma unroll
    for (int i = 0; i < 4; ++i) {
        size_t gn = (size_t)base + n0 + i;
        if (gn < (size_t)n_nodes) {
            __half2 p0 = __float22half2_rn(make_float2(accz[i][0], accz[i][1]));
            __half2 p1 = __float22half2_rn(make_float2(accz[i][2], accz[i][3]));
            ((__half2*)z)[gn * 32 + 2 * cg + 0] = p0;
            ((__half2*)z)[gn * 32 + 2 * cg + 1] = p1;
            ((float4*)r)[gn * 16 + cg] = make_float4(accr[i][0], accr[i][1], accr[i][2], accr[i][3]);
        }
    }
}

// h = PReLU( mean_j z[nbr_j] + r ). Wave per node, lane = channel, no LDS.
// z rows are fp16 (128 B) -- halves the dominant random-gather traffic.
__global__ __launch_bounds__(256) void gather_kernel(
        const __half* __restrict__ z,
        const float* r,
        const int* __restrict__ offsets,
        const int* __restrict__ sorted_src,
        const float* __restrict__ a,
        float* out) {
    const int lane = threadIdx.x & 63;
    const int node = (blockIdx.x << 2) + (threadIdx.x >> 6);

    const int beg = offsets[node];
    const int deg = offsets[node + 1] - beg;

    float acc = 0.0f;
    for (int j = 0; j < deg; j += 8) {
        int last = deg - 1;
        int s0 = sorted_src[beg + min(j + 0, last)];
        int s1 = sorted_src[beg + min(j + 1, last)];
        int s2 = sorted_src[beg + min(j + 2, last)];
        int s3 = sorted_src[beg + min(j + 3, last)];
        int s4 = sorted_src[beg + min(j + 4, last)];
        int s5 = sorted_src[beg + min(j + 5, last)];
        int s6 = sorted_src[beg + min(j + 6, last)];
        int s7 = sorted_src[beg + min(j + 7, last)];
        float v0 = __half2float(z[(size_t)s0 * C + lane]);
        float v1 = __half2float(z[(size_t)s1 * C + lane]);
        float v2 = __half2float(z[(size_t)s2 * C + lane]);
        float v3 = __half2float(z[(size_t)s3 * C + lane]);
        float v4 = __half2float(z[(size_t)s4 * C + lane]);
        float v5 = __half2float(z[(size_t)s5 * C + lane]);
        float v6 = __half2float(z[(size_t)s6 * C + lane]);
        float v7 = __half2float(z[(size_t)s7 * C + lane]);
        float sum = v0;
        sum += (j + 1 < deg) ? v1 : 0.0f;
        sum += (j + 2 < deg) ? v2 : 0.0f;
        sum += (j + 3 < deg) ? v3 : 0.0f;
        sum += (j + 4 < deg) ? v4 : 0.0f;
        sum += (j + 5 < deg) ? v5 : 0.0f;
        sum += (j + 6 < deg) ? v6 : 0.0f;
        sum += (j + 7 < deg) ? v7 : 0.0f;
        acc += sum;
    }
    float rv = r[(size_t)node * C + lane];
    float h = acc / (float)max(deg, 1) + rv;
    float av = a[lane];
    out[(size_t)node * C + lane] = h >= 0.0f ? h : av * h;
}

extern "C" void kernel_launch(void* const* d_in, const int* in_sizes, int n_in,
                              void* d_out, int out_size, void* d_ws, size_t ws_size,
                              hipStream_t stream) {
    const float* x    = (const float*)d_in[0];
    const int*   ei   = (const int*)d_in[1];
    const float* w_l0 = (const float*)d_in[2];
    const float* b_l0 = (const float*)d_in[3];
    const float* w_r0 = (const float*)d_in[4];
    const float* a0   = (const float*)d_in[5];
    const float* w_l1 = (const float*)d_in[6];
    const float* b_l1 = (const float*)d_in[7];
    const float* w_r1 = (const float*)d_in[8];
    const float* a1   = (const float*)d_in[9];
    float* out = (float*)d_out;

    const int* src = ei;            // edge_index[0, :]
    const int* dst = ei + N_EDGES;  // edge_index[1, :]

    // ws: cnt[N] | partial[512] | offsets[N+1] | cursor[N] | sorted_src[E] | Z(fp16, N*C) | B(fp32, N*C)
    int* cnt        = (int*)d_ws;
    int* partial    = cnt + N_NODES;
    int* offsets    = partial + 512;
    int* cursor     = offsets + (N_NODES + 1);
    int* sorted_src = cursor + N_NODES;
    __half* Z       = (__half*)(sorted_src + N_EDGES);
    float* B        = (float*)(Z + (size_t)N_NODES * C);

    hipMemsetAsync(cnt, 0, (size_t)N_NODES * sizeof(int), stream);

    const int eblocks = (N_EDGES + 255) / 256;
    const int nblocks = N_NODES / 4;          // gather grid (exact)
    const int dblocks = (N_NODES + 63) / 64;  // dense grid

    hist_kernel<<<eblocks, 256, 0, stream>>>(dst, cnt);
    scan1_kernel<<<SCAN_NB, 256, 0, stream>>>(cnt, partial);
    scan2_kernel<<<1, 512, 0, stream>>>(partial);
    scan3_kernel<<<SCAN_NB, 256, 0, stream>>>(cnt, partial, offsets, cursor);
    bucket_kernel<<<8 * COHORT, 256, 0, stream>>>(src, dst, cursor, sorted_src);

    // Layer 0: z=Z, r=B; gather writes h1 into B (row-aligned alias with r)
    dense_kernel<<<dblocks, 256, 0, stream>>>(x, w_l0, w_r0, b_l0, Z, B, N_NODES);
    gather_kernel<<<nblocks, 256, 0, stream>>>(Z, B, offsets, sorted_src, a0, B);

    // Layer 1: x=B, z=Z, r=B (in-place per-block safe); gather -> d_out
    dense_kernel<<<dblocks, 256, 0, stream>>>(B, w_l1, w_r1, b_l1, Z, B, N_NODES);
    gather_kernel<<<nblocks, 256, 0, stream>>>(Z, B, offsets, sorted_src, a1, out);
}